// Round 1
// baseline (51.760 us; speedup 1.0000x reference)
//
#include <hip/hip_runtime.h>

#define BB 8
#define HH 512
#define WW 512
#define HW (HH * WW)

__global__ __launch_bounds__(256) void bilateral_kernel(const float* __restrict__ in,
                                                        float* __restrict__ out) {
    int idx = blockIdx.x * 256 + threadIdx.x;          // over B*H*W = 2^21
    int x = idx & (WW - 1);
    int y = (idx >> 9) & (HH - 1);
    int b = idx >> 18;

    const float* p0 = in + (size_t)b * 3 * HW;
    const float* p1 = p0 + HW;
    const float* p2 = p1 + HW;
    int cidx = y * WW + x;

    float c0 = p0[cidx], c1 = p1[cidx], c2 = p2[cidx];

    // unnormalized 1-D spatial gaussian, sigma=21, x in {-3..3}; normalization
    // cancels in num/den
    const float sw[7] = {0.98984784f, 0.99547514f, 0.99886688f, 1.0f,
                         0.99886688f, 0.99547514f, 0.98984784f};

    float num0 = 0.f, num1 = 0.f, num2 = 0.f, den = 0.f;

    #pragma unroll
    for (int dy = 0; dy < 7; ++dy) {
        int my = y + dy - 3;
        my = my < 0 ? -my : my;                 // reflect low
        my = my >= HH ? 2 * HH - 2 - my : my;   // reflect high
        int rowbase = my * WW;
        float wy = sw[dy];
        #pragma unroll
        for (int dx = 0; dx < 7; ++dx) {
            int mx = x + dx - 3;
            mx = mx < 0 ? -mx : mx;
            mx = mx >= WW ? 2 * WW - 2 - mx : mx;
            int o = rowbase + mx;
            float q0 = p0[o], q1 = p1[o], q2 = p2[o];
            float d = fabsf(q0 - c0) + fabsf(q1 - c1) + fabsf(q2 - c2);
            // -0.5 / sigma_color^2 = -0.005
            float w = wy * sw[dx] * __expf(-0.005f * d * d);
            num0 += w * q0;
            num1 += w * q1;
            num2 += w * q2;
            den  += w;
        }
    }

    float inv = 1.0f / den;
    size_t obase = (size_t)b * 3 * HW + cidx;
    out[obase]          = num0 * inv;
    out[obase + HW]     = num1 * inv;
    out[obase + 2 * HW] = num2 * inv;
}

extern "C" void kernel_launch(void* const* d_in, const int* in_sizes, int n_in,
                              void* d_out, int out_size, void* d_ws, size_t ws_size,
                              hipStream_t stream) {
    const float* in = (const float*)d_in[0];
    float* out = (float*)d_out;
    int total = BB * HH * WW;                  // one thread per pixel (3 channels)
    int blocks = total / 256;                  // 8192
    bilateral_kernel<<<blocks, 256, 0, stream>>>(in, out);
}

// Round 3
// 51.724 us; speedup vs baseline: 1.0007x; 1.0007x over previous
//
#include <hip/hip_runtime.h>

#define BB 8
#define HH 512
#define WW 512
#define HW (HH * WW)

#define TW 32   // tile width (pixels)
#define TH 16   // tile height
#define LR 22   // tile rows in LDS  (TH + 6)
#define LC 38   // tile cols in LDS  (TW + 6)
#define LS 40   // LDS row stride; 40 % 32 == 8 -> 4-row wave access is 2-way (free)

__device__ __forceinline__ int reflect512(int v) {
    v = v < 0 ? -v : v;
    return v >= 512 ? 1022 - v : v;
}

__global__ __launch_bounds__(256) void bilateral_lds(const float* __restrict__ in,
                                                     float* __restrict__ out) {
    __shared__ float lds[3 * LR * LS];   // 10,560 B

    const int bx = blockIdx.x & 15;           // 512/TW = 16
    const int by = (blockIdx.x >> 4) & 31;    // 512/TH = 32
    const int b  = blockIdx.x >> 9;
    const int x0 = bx * TW, y0 = by * TH;
    const int tid = threadIdx.y * 16 + threadIdx.x;

    const float* __restrict__ src = in + (size_t)b * 3 * HW;

    // ---- stage tile + 3-halo into LDS (reflect handled once, here) ----
    for (int e = tid; e < 3 * LR * LC; e += 256) {
        int ch  = e / (LR * LC);
        int rem = e - ch * (LR * LC);
        int r   = rem / LC;
        int c   = rem - r * LC;
        int gy  = reflect512(y0 + r - 3);
        int gx  = reflect512(x0 + c - 3);
        lds[ch * (LR * LS) + r * LS + c] = src[ch * HW + gy * WW + gx];
    }
    __syncthreads();

    // ---- compute: each thread owns 2 adjacent output pixels ----
    const int tx = threadIdx.x, ty = threadIdx.y;
    const int wbase = ty * LS + 2 * tx;       // window row dy=0, col 0 (local)
    const float* L0 = lds;
    const float* L1 = lds + LR * LS;
    const float* L2 = lds + 2 * LR * LS;

    const float cA0 = L0[wbase + 3 * LS + 3], cB0 = L0[wbase + 3 * LS + 4];
    const float cA1 = L1[wbase + 3 * LS + 3], cB1 = L1[wbase + 3 * LS + 4];
    const float cA2 = L2[wbase + 3 * LS + 3], cB2 = L2[wbase + 3 * LS + 4];

    float nA0 = 0.f, nA1 = 0.f, nA2 = 0.f, dnA = 0.f;
    float nB0 = 0.f, nB1 = 0.f, nB2 = 0.f, dnB = 0.f;

    // unnormalized spatial gaussian (normalization cancels in num/den)
    const float swv[7] = {0.98984784f, 0.99547514f, 0.99886688f, 1.0f,
                          0.99886688f, 0.99547514f, 0.98984784f};
    const float K2 = -0.00721347520445f;      // (-0.5/10^2) * log2(e)

    #pragma unroll
    for (int dy = 0; dy < 7; ++dy) {
        const int ro = wbase + dy * LS;
        // 8 window columns per channel as float2 (8B-aligned: even col, even stride)
        float2 u0 = *(const float2*)(L0 + ro);
        float2 u1 = *(const float2*)(L0 + ro + 2);
        float2 u2 = *(const float2*)(L0 + ro + 4);
        float2 u3 = *(const float2*)(L0 + ro + 6);
        float2 v0 = *(const float2*)(L1 + ro);
        float2 v1 = *(const float2*)(L1 + ro + 2);
        float2 v2 = *(const float2*)(L1 + ro + 4);
        float2 v3 = *(const float2*)(L1 + ro + 6);
        float2 w0 = *(const float2*)(L2 + ro);
        float2 w1 = *(const float2*)(L2 + ro + 2);
        float2 w2 = *(const float2*)(L2 + ro + 4);
        float2 w3 = *(const float2*)(L2 + ro + 6);

        float q0[8] = {u0.x, u0.y, u1.x, u1.y, u2.x, u2.y, u3.x, u3.y};
        float q1[8] = {v0.x, v0.y, v1.x, v1.y, v2.x, v2.y, v3.x, v3.y};
        float q2[8] = {w0.x, w0.y, w1.x, w1.y, w2.x, w2.y, w3.x, w3.y};

        const float wy = swv[dy];
        #pragma unroll
        for (int dx = 0; dx < 7; ++dx) {
            const float sc = wy * swv[dx];    // literal after unroll
            {   // center A: window cols dx
                float d = fabsf(q0[dx] - cA0) + fabsf(q1[dx] - cA1) + fabsf(q2[dx] - cA2);
                float w = sc * __builtin_amdgcn_exp2f(K2 * (d * d));
                nA0 += w * q0[dx]; nA1 += w * q1[dx]; nA2 += w * q2[dx]; dnA += w;
            }
            {   // center B: window cols dx+1
                float d = fabsf(q0[dx+1] - cB0) + fabsf(q1[dx+1] - cB1) + fabsf(q2[dx+1] - cB2);
                float w = sc * __builtin_amdgcn_exp2f(K2 * (d * d));
                nB0 += w * q0[dx+1]; nB1 += w * q1[dx+1]; nB2 += w * q2[dx+1]; dnB += w;
            }
        }
    }

    const float iA = 1.0f / dnA, iB = 1.0f / dnB;
    size_t ob = (size_t)b * 3 * HW + (size_t)(y0 + ty) * WW + x0 + 2 * tx;
    *(float2*)(out + ob)          = make_float2(nA0 * iA, nB0 * iB);
    *(float2*)(out + ob + HW)     = make_float2(nA1 * iA, nB1 * iB);
    *(float2*)(out + ob + 2 * HW) = make_float2(nA2 * iA, nB2 * iB);
}

extern "C" void kernel_launch(void* const* d_in, const int* in_sizes, int n_in,
                              void* d_out, int out_size, void* d_ws, size_t ws_size,
                              hipStream_t stream) {
    const float* in = (const float*)d_in[0];
    float* out = (float*)d_out;
    dim3 block(16, 16, 1);
    int blocks = (WW / TW) * (HH / TH) * BB;   // 16*32*8 = 4096
    bilateral_lds<<<blocks, block, 0, stream>>>(in, out);
}